// Round 12
// baseline (241.434 us; speedup 1.0000x reference)
//
#include <hip/hip_runtime.h>

// MHA: out = softmax((XQ Wq^T + bq)(XK Wk^T + bk)^T / sqrt(64)) (XV Wv^T + bv) Wo^T + bo
// B=4, S=2048, D=1024, H=16, Dh=64. All matmuls bf16 MFMA 16x16x32, fp32 accum.
//
// v12 = v11 with the gemm_o call-site cast fixed ((float*)d_out).
// cvt3 eliminated: fp32->bf16 conversion fused into GEMM staging. fp32
// operands are reg-staged (8x dwordx4 -> 16x cvt_pk -> 4x ds_write_b128 into
// the same swizzled LDS layout); bf16 operands keep global_load_lds.

#define BATCH 4
#define SEQ   2048
#define NH    16
#define DH    64
#define DM    1024
#define LOG2E 1.4426950408889634f
#define SCALE_Q (0.125f * LOG2E)   // folded into Q projection epilogue

typedef __attribute__((ext_vector_type(8))) short s16x8;
typedef __attribute__((ext_vector_type(4))) float f32x4;
typedef __attribute__((ext_vector_type(4))) unsigned int u32x4;
typedef const __attribute__((address_space(1))) unsigned int* gas1;
typedef __attribute__((address_space(3))) unsigned int* las3;

__device__ __forceinline__ unsigned short f2bf(float f) {
  unsigned int u = __float_as_uint(f);
  u += 0x7FFFu + ((u >> 16) & 1u);   // RTNE
  return (unsigned short)(u >> 16);
}

__device__ __forceinline__ unsigned int cvt_pk_bf16(float lo, float hi) {
  unsigned int r;
  asm("v_cvt_pk_bf16_f32 %0, %1, %2" : "=v"(r) : "v"(lo), "v"(hi));
  return r;
}

__device__ __forceinline__ f32x4 vmax4(f32x4 a, f32x4 b) {
  f32x4 r;
  r[0] = fmaxf(a[0], b[0]); r[1] = fmaxf(a[1], b[1]);
  r[2] = fmaxf(a[2], b[2]); r[3] = fmaxf(a[3], b[3]);
  return r;
}

// ---------------- fp32 -> bf16, 4 weight matrices in one launch ----------------
__global__ __launch_bounds__(256) void cvt4_k(const float* __restrict__ s0,
                                              const float* __restrict__ s1,
                                              const float* __restrict__ s2,
                                              const float* __restrict__ s3,
                                              unsigned short* __restrict__ d0,
                                              unsigned short* __restrict__ d1,
                                              unsigned short* __restrict__ d2,
                                              unsigned short* __restrict__ d3, int n4) {
  const float* s = blockIdx.y == 0 ? s0 : blockIdx.y == 1 ? s1 : blockIdx.y == 2 ? s2 : s3;
  unsigned short* d = blockIdx.y == 0 ? d0 : blockIdx.y == 1 ? d1 : blockIdx.y == 2 ? d2 : d3;
  int i = blockIdx.x * 256 + threadIdx.x;
  if (i < n4) {
    float4 v = ((const float4*)s)[i];
    ushort4 o;
    o.x = f2bf(v.x); o.y = f2bf(v.y); o.z = f2bf(v.z); o.w = f2bf(v.w);
    ((ushort4*)d)[i] = o;
  }
}

// ---------------- GEMM core: C[M,N] = scale*(A[M,K] * B[N,K]^T + bias) ----------------
// AF32/BF32: that operand is fp32 in global memory; staged via regs with
// on-the-fly cvt_pk into the SAME swizzled bf16 LDS layout.
template<bool BIAS_ROW, bool OUT_F32, bool AF32, bool BF32>
__device__ __forceinline__ void gemm_core(const void* __restrict__ Ain,
                                          const void* __restrict__ Bin,
                                          const float* __restrict__ bias,
                                          void* __restrict__ Cout,
                                          int M, int N, int K, int tM, int tN, float scale,
                                          unsigned short* As, unsigned short* Bs) {
  const int tid = threadIdx.x;
  const int wave = tid >> 6, lane = tid & 63;
  const int lr = lane & 15, lh = lane >> 4;
  const int wm = (wave >> 1) * 64, wn = (wave & 1) * 64;
  f32x4 acc[4][4] = {};

  for (int k0 = 0; k0 < K; k0 += 64) {
    __syncthreads();
    // ---- staging ----
    {
#pragma unroll
      for (int i = 0; i < 4; ++i) {
        const int slot = wave * 256 + i * 64 + lane;
        const int row = slot >> 3;
        const int cg = (slot & 7) ^ (row & 7);
        if (!AF32) {
          const unsigned short* ga = (const unsigned short*)Ain + (size_t)(tM * 128 + row) * K + k0 + cg * 8;
          __builtin_amdgcn_global_load_lds((gas1)ga, (las3)(As + (wave * 256 + i * 64) * 8), 16, 0, 0);
        }
        if (!BF32) {
          const unsigned short* gb = (const unsigned short*)Bin + (size_t)(tN * 128 + row) * K + k0 + cg * 8;
          __builtin_amdgcn_global_load_lds((gas1)gb, (las3)(Bs + (wave * 256 + i * 64) * 8), 16, 0, 0);
        }
      }
      // fp32 operand: reg-stage + convert (issue all loads, then cvt+write)
      if (AF32 || BF32) {
        float4 fa[8];
#pragma unroll
        for (int i = 0; i < 4; ++i) {
          const int slot = wave * 256 + i * 64 + lane;
          const int row = slot >> 3;
          const int cg = (slot & 7) ^ (row & 7);
          const float* g = AF32
              ? (const float*)Ain + (size_t)(tM * 128 + row) * K + k0 + cg * 8
              : (const float*)Bin + (size_t)(tN * 128 + row) * K + k0 + cg * 8;
          fa[i * 2]     = *(const float4*)g;
          fa[i * 2 + 1] = *(const float4*)(g + 4);
        }
        unsigned short* dst = AF32 ? As : Bs;
#pragma unroll
        for (int i = 0; i < 4; ++i) {
          const int slot = wave * 256 + i * 64 + lane;
          u32x4 pu;
          pu[0] = cvt_pk_bf16(fa[i * 2].x, fa[i * 2].y);
          pu[1] = cvt_pk_bf16(fa[i * 2].z, fa[i * 2].w);
          pu[2] = cvt_pk_bf16(fa[i * 2 + 1].x, fa[i * 2 + 1].y);
          pu[3] = cvt_pk_bf16(fa[i * 2 + 1].z, fa[i * 2 + 1].w);
          *(u32x4*)(dst + slot * 8) = pu;
        }
      }
    }
    __syncthreads();

    s16x8 af[4][2], bfr[4][2];
#pragma unroll
    for (int mt = 0; mt < 4; ++mt) {
#pragma unroll
      for (int kt = 0; kt < 2; ++kt) {
        const int ra = wm + mt * 16 + lr;
        af[mt][kt] = *(const s16x8*)(As + ra * 64 + (((kt * 4 + lh) ^ (ra & 7)) * 8));
        const int rb = wn + mt * 16 + lr;
        bfr[mt][kt] = *(const s16x8*)(Bs + rb * 64 + (((kt * 4 + lh) ^ (rb & 7)) * 8));
      }
    }
#pragma unroll
    for (int mt = 0; mt < 4; ++mt) {
#pragma unroll
      for (int nt = 0; nt < 4; ++nt) {
        acc[mt][nt] = __builtin_amdgcn_mfma_f32_16x16x32_bf16(af[mt][0], bfr[nt][0], acc[mt][nt], 0, 0, 0);
        acc[mt][nt] = __builtin_amdgcn_mfma_f32_16x16x32_bf16(af[mt][1], bfr[nt][1], acc[mt][nt], 0, 0, 0);
      }
    }
  }

#pragma unroll
  for (int mt = 0; mt < 4; ++mt) {
#pragma unroll
    for (int nt = 0; nt < 4; ++nt) {
      const int row0 = tM * 128 + wm + mt * 16 + lh * 4;
      const int col  = tN * 128 + wn + nt * 16 + lr;
      const float bc = BIAS_ROW ? 0.f : bias[col];
#pragma unroll
      for (int r = 0; r < 4; ++r) {
        const float v = (acc[mt][nt][r] + (BIAS_ROW ? bias[row0 + r] : bc)) * scale;
        if (OUT_F32) ((float*)Cout)[(size_t)(row0 + r) * N + col] = v;
        else ((unsigned short*)Cout)[(size_t)(row0 + r) * N + col] = f2bf(v);
      }
    }
  }
}

// O projection: bf16 x bf16 -> fp32
__global__ __launch_bounds__(256) void gemm_o(const unsigned short* __restrict__ A,
                                              const unsigned short* __restrict__ Bm,
                                              const float* __restrict__ bias,
                                              float* __restrict__ Cout, int M, int N, int K) {
  __shared__ unsigned short As[128 * 64];
  __shared__ unsigned short Bs[128 * 64];
  gemm_core<false, true, false, false>(A, Bm, bias, Cout, M, N, K,
                                       blockIdx.y, blockIdx.x, 1.0f, As, Bs);
}

// V projection (transposed out): A = Wv bf16, B = XV fp32 (fused cvt), bias row.
__global__ __launch_bounds__(256) void gemm_v(const unsigned short* __restrict__ A,
                                              const float* __restrict__ Bm,
                                              const float* __restrict__ bias,
                                              unsigned short* __restrict__ Cout,
                                              int M, int N, int K) {
  __shared__ unsigned short As[128 * 64];
  __shared__ unsigned short Bs[128 * 64];
  gemm_core<true, false, false, true>(A, Bm, bias, Cout, M, N, K,
                                      blockIdx.y, blockIdx.x, 1.0f, As, Bs);
}

// Q and K projections: A = raw q/k fp32 (fused cvt), W bf16. Q pre-scaled.
__global__ __launch_bounds__(256) void gemm_qk(const float* __restrict__ A0,
                                               const float* __restrict__ A1,
                                               const unsigned short* __restrict__ W0,
                                               const unsigned short* __restrict__ W1,
                                               const float* __restrict__ c0,
                                               const float* __restrict__ c1,
                                               void* __restrict__ C0, void* __restrict__ C1,
                                               int M, int N, int K) {
  __shared__ unsigned short As[128 * 64];
  __shared__ unsigned short Bs[128 * 64];
  if (blockIdx.z == 0)
    gemm_core<false, false, true, false>(A0, W0, c0, C0, M, N, K,
                                         blockIdx.y, blockIdx.x, SCALE_Q, As, Bs);
  else
    gemm_core<false, false, true, false>(A1, W1, c1, C1, M, N, K,
                                         blockIdx.y, blockIdx.x, 1.0f, As, Bs);
}

// ---------------- fused flash attention (v10, frozen) ----------------
__global__ __launch_bounds__(256, 4) void attn_k(const unsigned short* __restrict__ Q,
                                                 const unsigned short* __restrict__ Kp,
                                                 const unsigned short* __restrict__ Vt,
                                                 unsigned short* __restrict__ AO) {
  __shared__ unsigned short Ks[2][64 * 64];     // [kv][d]  2 x 8KB
  __shared__ unsigned short Vs[2][64 * 64];     // [d][kv]  2 x 8KB
  __shared__ unsigned short Ps[4][16 * 64];     // per-wave [q 16][16 x 8B slots], 8KB
  const int tid = threadIdx.x;
  const int w = tid >> 6, lane = tid & 63;
  const int lr = lane & 15, lh = lane >> 4;
  const int sw = lr & 7;          // 3-bit key for 64-wide K/V rows

  // XCD-aware swizzle: 8 consecutive (b,h) pairs per XCD (per-XCD KV ~4MB = L2)
  const int id = blockIdx.x;                    // 0..1023
  const int g  = (id & 7) * 128 + (id >> 3);    // bijective (1024 % 8 == 0)
  const int qt = g & 15;
  const int hb = g >> 4;
  const int h = hb & 15, b = hb >> 4;

  s16x8 qf[2][2];
#pragma unroll
  for (int qb = 0; qb < 2; ++qb)
#pragma unroll
    for (int kt = 0; kt < 2; ++kt)
      qf[qb][kt] = *(const s16x8*)(Q + (size_t)(b * SEQ + qt * 128 + w * 32 + qb * 16 + lr) * DM
                                     + h * DH + kt * 32 + lh * 8);
  asm volatile("s_waitcnt vmcnt(0)" ::: "memory");   // qf resident; vmcnt accounting clean
  __builtin_amdgcn_sched_barrier(0);

  f32x4 o[2][4] = {};
  float m_run[2] = {-1e30f, -1e30f};
  float l_run[2] = {0.f, 0.f};
  unsigned short* Pw = Ps[w];

  const unsigned short* Kbase = Kp + (size_t)b * SEQ * DM + h * DH;
  const unsigned short* Vbase = Vt + (size_t)h * DH * (BATCH * SEQ) + (size_t)b * SEQ;

  // per-lane staging pointers (advance by constant strides per tile)
  const int slot0 = w * 64 + lane, slot1 = 256 + w * 64 + lane;
  const int r0 = slot0 >> 3, c0 = (slot0 & 7) ^ (r0 & 7);
  const int r1 = slot1 >> 3, c1 = (slot1 & 7) ^ (r1 & 7);
  const unsigned short* gk0 = Kbase + (size_t)r0 * DM + c0 * 8;
  const unsigned short* gk1 = Kbase + (size_t)r1 * DM + c1 * 8;
  const unsigned short* gv0 = Vbase + (size_t)r0 * (BATCH * SEQ) + c0 * 8;
  const unsigned short* gv1 = Vbase + (size_t)r1 * (BATCH * SEQ) + c1 * 8;
  const int dst0 = (w * 64) * 8, dst1 = (256 + w * 64) * 8;

  auto stage = [&](int buf) {
    __builtin_amdgcn_global_load_lds((gas1)gk0, (las3)(&Ks[buf][dst0]), 16, 0, 0);
    __builtin_amdgcn_global_load_lds((gas1)gk1, (las3)(&Ks[buf][dst1]), 16, 0, 0);
    __builtin_amdgcn_global_load_lds((gas1)gv0, (las3)(&Vs[buf][dst0]), 16, 0, 0);
    __builtin_amdgcn_global_load_lds((gas1)gv1, (las3)(&Vs[buf][dst1]), 16, 0, 0);
    gk0 += 64 * DM; gk1 += 64 * DM; gv0 += 64; gv1 += 64;
  };

  stage(0);
  for (int t = 0; t < 32; ++t) {
    const int cur = t & 1;
    if (t < 31) {
      stage(cur ^ 1);                                 // prefetch next tile
      asm volatile("s_waitcnt vmcnt(4)" ::: "memory");// cur's 4 loads done; next 4 in flight
    } else {
      asm volatile("s_waitcnt vmcnt(0)" ::: "memory");
    }
    __builtin_amdgcn_s_barrier();
    __builtin_amdgcn_sched_barrier(0);
    const unsigned short* Kc = Ks[cur];
    const unsigned short* Vc = Vs[cur];

    // QK^T (swapped operands): rows = kv, cols = q; output already in exp2 domain
    f32x4 s[2][4] = {};
    __builtin_amdgcn_s_setprio(1);
#pragma unroll
    for (int nt = 0; nt < 4; ++nt) {
#pragma unroll
      for (int kt = 0; kt < 2; ++kt) {
        const s16x8 kf = *(const s16x8*)(Kc + (nt * 16 + lr) * 64 + (((kt * 4 + lh) ^ sw) * 8));
        s[0][nt] = __builtin_amdgcn_mfma_f32_16x16x32_bf16(kf, qf[0][kt], s[0][nt], 0, 0, 0);
        s[1][nt] = __builtin_amdgcn_mfma_f32_16x16x32_bf16(kf, qf[1][kt], s[1][nt], 0, 0, 0);
      }
    }
    __builtin_amdgcn_s_setprio(0);

    // online softmax, lane-local (q = lr), defer-max rescale; exp in place,
    // then pack BOTH qb to bf16 regs (s dies -> pk, 16 regs)
    uint2 pk[2][4];
#pragma unroll
    for (int qb = 0; qb < 2; ++qb) {
      const f32x4 m03 = vmax4(vmax4(s[qb][0], s[qb][1]), vmax4(s[qb][2], s[qb][3]));
      float mx = fmaxf(fmaxf(m03[0], m03[1]), fmaxf(m03[2], m03[3]));
      mx = fmaxf(mx, __shfl_xor(mx, 16));
      mx = fmaxf(mx, __shfl_xor(mx, 32));
      if (!__all(mx - m_run[qb] <= 11.5f)) {   // exp2-domain defer threshold
        const float al = __builtin_amdgcn_exp2f(m_run[qb] - mx);
        m_run[qb] = mx;
        l_run[qb] *= al;
#pragma unroll
        for (int dt = 0; dt < 4; ++dt) o[qb][dt] *= al;
      }
      const float base = m_run[qb];
#pragma unroll
      for (int nt = 0; nt < 4; ++nt)
#pragma unroll
        for (int r = 0; r < 4; ++r)
          s[qb][nt][r] = __builtin_amdgcn_exp2f(s[qb][nt][r] - base);
      const f32x4 st = (s[qb][0] + s[qb][1]) + (s[qb][2] + s[qb][3]);
      float rs = (st[0] + st[1]) + (st[2] + st[3]);
      rs += __shfl_xor(rs, 16);
      rs += __shfl_xor(rs, 32);
      l_run[qb] += rs;
#pragma unroll
      for (int nt = 0; nt < 4; ++nt) {
        pk[qb][nt].x = cvt_pk_bf16(s[qb][nt][0], s[qb][nt][1]);
        pk[qb][nt].y = cvt_pk_bf16(s[qb][nt][2], s[qb][nt][3]);
      }
    }

    // V-fragments: each Vs byte read exactly once per wave (8 b128)
    s16x8 vf[8];
#pragma unroll
    for (int hf = 0; hf < 2; ++hf)
#pragma unroll
      for (int dt = 0; dt < 4; ++dt)
        vf[hf * 4 + dt] = *(const s16x8*)(Vc + (dt * 16 + lr) * 64 + (((hf * 4 + lh) ^ sw) * 8));

    // PV per qb through the rotated per-wave P buffer; V from registers
#pragma unroll
    for (int qb = 0; qb < 2; ++qb) {
#pragma unroll
      for (int nt = 0; nt < 4; ++nt)
        *(uint2*)(Pw + lr * 64 + (((nt * 4 + lh + lr) & 15) * 4)) = pk[qb][nt];
#pragma unroll
      for (int hf = 0; hf < 2; ++hf) {
        const int ca = (hf * 8 + lh * 2 + lr) & 15;
        const int cb = (hf * 8 + lh * 2 + 1 + lr) & 15;
        const uint2 lo = *(const uint2*)(Pw + lr * 64 + ca * 4);
        const uint2 hi = *(const uint2*)(Pw + lr * 64 + cb * 4);
        u32x4 pu;
        pu[0] = lo.x; pu[1] = lo.y; pu[2] = hi.x; pu[3] = hi.y;
        const s16x8 pf = __builtin_bit_cast(s16x8, pu);
        __builtin_amdgcn_s_setprio(1);
#pragma unroll
        for (int dt = 0; dt < 4; ++dt)
          o[qb][dt] = __builtin_amdgcn_mfma_f32_16x16x32_bf16(vf[hf * 4 + dt], pf, o[qb][dt], 0, 0, 0);
        __builtin_amdgcn_s_setprio(0);
      }
    }
    __builtin_amdgcn_sched_barrier(0);
    __builtin_amdgcn_s_barrier();   // all waves done reading buf[cur] before it's restaged
  }

  // epilogue: normalize, pack pairs, store (O[q=lr][d])
#pragma unroll
  for (int qb = 0; qb < 2; ++qb) {
    const float rl = __builtin_amdgcn_rcpf(l_run[qb]);
    unsigned short* orow = AO + (size_t)(b * SEQ + qt * 128 + w * 32 + qb * 16 + lr) * DM + h * DH;
#pragma unroll
    for (int dt = 0; dt < 4; ++dt) {
      *(unsigned int*)(orow + dt * 16 + lh * 4)     = cvt_pk_bf16(o[qb][dt][0] * rl, o[qb][dt][1] * rl);
      *(unsigned int*)(orow + dt * 16 + lh * 4 + 2) = cvt_pk_bf16(o[qb][dt][2] * rl, o[qb][dt][3] * rl);
    }
  }
}

extern "C" void kernel_launch(void* const* d_in, const int* in_sizes, int n_in,
                              void* d_out, int out_size, void* d_ws, size_t ws_size,
                              hipStream_t stream) {
  const float* q   = (const float*)d_in[0];
  const float* k   = (const float*)d_in[1];
  const float* v   = (const float*)d_in[2];
  const float* W_q = (const float*)d_in[3];
  const float* b_q = (const float*)d_in[4];
  const float* W_k = (const float*)d_in[5];
  const float* b_k = (const float*)d_in[6];
  const float* W_v = (const float*)d_in[7];
  const float* b_v = (const float*)d_in[8];
  const float* W_o = (const float*)d_in[9];
  const float* b_o = (const float*)d_in[10];

  const size_t SD  = (size_t)BATCH * SEQ * DM;          // 8,388,608 elems
  const size_t SDB = SD * 2;                            // bytes per bf16 buffer
  const size_t D2  = (size_t)DM * DM;                   // 1,048,576 elems
  if (ws_size < 5 * SDB + D2 * 2) return;               // ~86 MB

  char* base = (char*)d_ws;
  unsigned short* B0 = (unsigned short*)(base);             // AO
  unsigned short* B1 = (unsigned short*)(base + 1 * SDB);   // Vt
  unsigned short* B3 = (unsigned short*)(base + 3 * SDB);   // Qp (pre-scaled)
  unsigned short* B4 = (unsigned short*)(base + 4 * SDB);   // Kp
  unsigned short* Wb = (unsigned short*)(base + 5 * SDB);   // Wo bf16 (2MB)

  // bf16 Wq/Wk/Wv parked in d_out's front 6MB (fully overwritten by O-GEMM later)
  unsigned short* dW0 = (unsigned short*)d_out;             // Wq
  unsigned short* dW1 = dW0 + D2;                           // Wk
  unsigned short* dW2 = dW0 + 2 * D2;                       // Wv

  const int nD24 = (int)(D2 / 4);
  const dim3 blk(256);

  cvt4_k<<<dim3(nD24 / 256, 4), blk, 0, stream>>>(W_q, W_k, W_v, W_o, dW0, dW1, dW2, Wb, nD24);
  // Q and K projections (one dispatch; A = raw fp32 q/k with fused conversion)
  gemm_qk<<<dim3(DM / 128, (BATCH * SEQ) / 128, 2), blk, 0, stream>>>(
      q, k, dW0, dW1, b_q, b_k, B3, B4, BATCH * SEQ, DM, DM);
  // V projection, transposed output: Vt[d, b*S+s]; B = raw fp32 v (fused cvt)
  gemm_v<<<dim3((BATCH * SEQ) / 128, DM / 128), blk, 0, stream>>>(
      dW2, v, b_v, B1, DM, BATCH * SEQ, DM);
  // fused attention
  attn_k<<<dim3(16 * NH * BATCH), blk, 0, stream>>>(B3, B4, B1, B0);
  // output projection -> fp32
  gemm_o<<<dim3(DM / 128, (BATCH * SEQ) / 128), blk, 0, stream>>>(
      B0, Wb, b_o, (float*)d_out, BATCH * SEQ, DM, DM);
}

// Round 13
// 230.572 us; speedup vs baseline: 1.0471x; 1.0471x over previous
//
#include <hip/hip_runtime.h>

// MHA: out = softmax((XQ Wq^T + bq)(XK Wk^T + bk)^T / sqrt(64)) (XV Wv^T + bv) Wo^T + bo
// B=4, S=2048, D=1024, H=16, Dh=64. All matmuls bf16 MFMA 16x16x32, fp32 accum.
//
// v13 = v10 pipeline (cvt3 + cvt4 + plain bf16 GEMMs — v12's fused-cvt staging
// reverted, it cost more than cvt3 saved) + attn addressing diet: all LDS
// fragment addresses precomputed as loop-invariant pointers (P fully; K/V as
// buffer-0 pointers + one uniform curB byte offset). No unroll, no layout
// change, same math.

#define BATCH 4
#define SEQ   2048
#define NH    16
#define DH    64
#define DM    1024
#define LOG2E 1.4426950408889634f
#define SCALE_Q (0.125f * LOG2E)   // folded into Q projection epilogue

typedef __attribute__((ext_vector_type(8))) short s16x8;
typedef __attribute__((ext_vector_type(4))) float f32x4;
typedef __attribute__((ext_vector_type(4))) unsigned int u32x4;
typedef const __attribute__((address_space(1))) unsigned int* gas1;
typedef __attribute__((address_space(3))) unsigned int* las3;

__device__ __forceinline__ unsigned short f2bf(float f) {
  unsigned int u = __float_as_uint(f);
  u += 0x7FFFu + ((u >> 16) & 1u);   // RTNE
  return (unsigned short)(u >> 16);
}

__device__ __forceinline__ unsigned int cvt_pk_bf16(float lo, float hi) {
  unsigned int r;
  asm("v_cvt_pk_bf16_f32 %0, %1, %2" : "=v"(r) : "v"(lo), "v"(hi));
  return r;
}

__device__ __forceinline__ f32x4 vmax4(f32x4 a, f32x4 b) {
  f32x4 r;
  r[0] = fmaxf(a[0], b[0]); r[1] = fmaxf(a[1], b[1]);
  r[2] = fmaxf(a[2], b[2]); r[3] = fmaxf(a[3], b[3]);
  return r;
}

// ---------------- fp32 -> bf16, 3 tensors in one launch ----------------
__global__ __launch_bounds__(256) void cvt3_k(const float* __restrict__ s0,
                                              const float* __restrict__ s1,
                                              const float* __restrict__ s2,
                                              unsigned short* __restrict__ d0,
                                              unsigned short* __restrict__ d1,
                                              unsigned short* __restrict__ d2, int n4) {
  const float* s = blockIdx.y == 0 ? s0 : blockIdx.y == 1 ? s1 : s2;
  unsigned short* d = blockIdx.y == 0 ? d0 : blockIdx.y == 1 ? d1 : d2;
  int i = blockIdx.x * 256 + threadIdx.x;
  if (i < n4) {
    float4 v = ((const float4*)s)[i];
    ushort4 o;
    o.x = f2bf(v.x); o.y = f2bf(v.y); o.z = f2bf(v.z); o.w = f2bf(v.w);
    ((ushort4*)d)[i] = o;
  }
}

// ---------------- fp32 -> bf16, 4 weight matrices in one launch ----------------
__global__ __launch_bounds__(256) void cvt4_k(const float* __restrict__ s0,
                                              const float* __restrict__ s1,
                                              const float* __restrict__ s2,
                                              const float* __restrict__ s3,
                                              unsigned short* __restrict__ d0,
                                              unsigned short* __restrict__ d1,
                                              unsigned short* __restrict__ d2,
                                              unsigned short* __restrict__ d3, int n4) {
  const float* s = blockIdx.y == 0 ? s0 : blockIdx.y == 1 ? s1 : blockIdx.y == 2 ? s2 : s3;
  unsigned short* d = blockIdx.y == 0 ? d0 : blockIdx.y == 1 ? d1 : blockIdx.y == 2 ? d2 : d3;
  int i = blockIdx.x * 256 + threadIdx.x;
  if (i < n4) {
    float4 v = ((const float4*)s)[i];
    ushort4 o;
    o.x = f2bf(v.x); o.y = f2bf(v.y); o.z = f2bf(v.z); o.w = f2bf(v.w);
    ((ushort4*)d)[i] = o;
  }
}

// ---------------- GEMM core: C[M,N] = scale*(A[M,K] * B[N,K]^T + bias) ----------------
template<bool BIAS_ROW, bool OUT_F32>
__device__ __forceinline__ void gemm_core(const unsigned short* __restrict__ A,
                                          const unsigned short* __restrict__ Bm,
                                          const float* __restrict__ bias,
                                          void* __restrict__ Cout,
                                          int M, int N, int K, int tM, int tN, float scale,
                                          unsigned short* As, unsigned short* Bs) {
  const int tid = threadIdx.x;
  const int wave = tid >> 6, lane = tid & 63;
  const int lr = lane & 15, lh = lane >> 4;
  const int wm = (wave >> 1) * 64, wn = (wave & 1) * 64;
  f32x4 acc[4][4] = {};

  for (int k0 = 0; k0 < K; k0 += 64) {
    __syncthreads();
#pragma unroll
    for (int i = 0; i < 4; ++i) {
      const int slot = wave * 256 + i * 64 + lane;
      const int row = slot >> 3;
      const int cg = (slot & 7) ^ (row & 7);   // inverse-swizzled source chunk
      const unsigned short* ga = A  + (size_t)(tM * 128 + row) * K + k0 + cg * 8;
      const unsigned short* gb = Bm + (size_t)(tN * 128 + row) * K + k0 + cg * 8;
      __builtin_amdgcn_global_load_lds((gas1)ga, (las3)(As + (wave * 256 + i * 64) * 8), 16, 0, 0);
      __builtin_amdgcn_global_load_lds((gas1)gb, (las3)(Bs + (wave * 256 + i * 64) * 8), 16, 0, 0);
    }
    __syncthreads();

    s16x8 af[4][2], bfr[4][2];
#pragma unroll
    for (int mt = 0; mt < 4; ++mt) {
#pragma unroll
      for (int kt = 0; kt < 2; ++kt) {
        const int ra = wm + mt * 16 + lr;
        af[mt][kt] = *(const s16x8*)(As + ra * 64 + (((kt * 4 + lh) ^ (ra & 7)) * 8));
        const int rb = wn + mt * 16 + lr;
        bfr[mt][kt] = *(const s16x8*)(Bs + rb * 64 + (((kt * 4 + lh) ^ (rb & 7)) * 8));
      }
    }
#pragma unroll
    for (int mt = 0; mt < 4; ++mt) {
#pragma unroll
      for (int nt = 0; nt < 4; ++nt) {
        acc[mt][nt] = __builtin_amdgcn_mfma_f32_16x16x32_bf16(af[mt][0], bfr[nt][0], acc[mt][nt], 0, 0, 0);
        acc[mt][nt] = __builtin_amdgcn_mfma_f32_16x16x32_bf16(af[mt][1], bfr[nt][1], acc[mt][nt], 0, 0, 0);
      }
    }
  }

#pragma unroll
  for (int mt = 0; mt < 4; ++mt) {
#pragma unroll
    for (int nt = 0; nt < 4; ++nt) {
      const int row0 = tM * 128 + wm + mt * 16 + lh * 4;
      const int col  = tN * 128 + wn + nt * 16 + lr;
      const float bc = BIAS_ROW ? 0.f : bias[col];
#pragma unroll
      for (int r = 0; r < 4; ++r) {
        const float v = (acc[mt][nt][r] + (BIAS_ROW ? bias[row0 + r] : bc)) * scale;
        if (OUT_F32) ((float*)Cout)[(size_t)(row0 + r) * N + col] = v;
        else ((unsigned short*)Cout)[(size_t)(row0 + r) * N + col] = f2bf(v);
      }
    }
  }
}

template<bool BIAS_ROW, bool OUT_F32>
__global__ __launch_bounds__(256) void gemm_bt(const unsigned short* __restrict__ A,
                                               const unsigned short* __restrict__ Bm,
                                               const float* __restrict__ bias,
                                               void* __restrict__ Cout, int M, int N, int K) {
  __shared__ unsigned short As[128 * 64];
  __shared__ unsigned short Bs[128 * 64];
  gemm_core<BIAS_ROW, OUT_F32>(A, Bm, bias, Cout, M, N, K, blockIdx.y, blockIdx.x, 1.0f, As, Bs);
}

// Q and K projections merged: blockIdx.z selects the operand set. Q pre-scaled.
__global__ __launch_bounds__(256) void gemm_qk(const unsigned short* __restrict__ A0,
                                               const unsigned short* __restrict__ A1,
                                               const unsigned short* __restrict__ W0,
                                               const unsigned short* __restrict__ W1,
                                               const float* __restrict__ c0,
                                               const float* __restrict__ c1,
                                               void* __restrict__ C0, void* __restrict__ C1,
                                               int M, int N, int K) {
  __shared__ unsigned short As[128 * 64];
  __shared__ unsigned short Bs[128 * 64];
  if (blockIdx.z == 0)
    gemm_core<false, false>(A0, W0, c0, C0, M, N, K, blockIdx.y, blockIdx.x, SCALE_Q, As, Bs);
  else
    gemm_core<false, false>(A1, W1, c1, C1, M, N, K, blockIdx.y, blockIdx.x, 1.0f, As, Bs);
}

// ---------------- fused flash attention v13 ----------------
// v10 structure; all LDS fragment addresses precomputed (loop-invariant).
__global__ __launch_bounds__(256, 4) void attn_k(const unsigned short* __restrict__ Q,
                                                 const unsigned short* __restrict__ Kp,
                                                 const unsigned short* __restrict__ Vt,
                                                 unsigned short* __restrict__ AO) {
  __shared__ unsigned short Ks[2][64 * 64];     // [kv][d]  2 x 8KB
  __shared__ unsigned short Vs[2][64 * 64];     // [d][kv]  2 x 8KB
  __shared__ unsigned short Ps[4][16 * 64];     // per-wave [q 16][16 x 8B slots], 8KB
  const int tid = threadIdx.x;
  const int w = tid >> 6, lane = tid & 63;
  const int lr = lane & 15, lh = lane >> 4;
  const int sw = lr & 7;          // 3-bit key for 64-wide K/V rows

  // XCD-aware swizzle: 8 consecutive (b,h) pairs per XCD
  const int id = blockIdx.x;                    // 0..1023
  const int g  = (id & 7) * 128 + (id >> 3);    // bijective (1024 % 8 == 0)
  const int qt = g & 15;
  const int hb = g >> 4;
  const int h = hb & 15, b = hb >> 4;

  s16x8 qf[2][2];
#pragma unroll
  for (int qb = 0; qb < 2; ++qb)
#pragma unroll
    for (int kt = 0; kt < 2; ++kt)
      qf[qb][kt] = *(const s16x8*)(Q + (size_t)(b * SEQ + qt * 128 + w * 32 + qb * 16 + lr) * DM
                                     + h * DH + kt * 32 + lh * 8);
  asm volatile("s_waitcnt vmcnt(0)" ::: "memory");   // qf resident; vmcnt accounting clean
  __builtin_amdgcn_sched_barrier(0);

  f32x4 o[2][4] = {};
  float m_run[2] = {-1e30f, -1e30f};
  float l_run[2] = {0.f, 0.f};
  unsigned short* Pw = Ps[w];

  // ---- precomputed loop-invariant LDS addresses ----
  const char* kf0[4][2];                 // K frag, buffer 0
#pragma unroll
  for (int nt = 0; nt < 4; ++nt)
#pragma unroll
    for (int kt = 0; kt < 2; ++kt)
      kf0[nt][kt] = (const char*)(Ks[0] + (nt * 16 + lr) * 64 + (((kt * 4 + lh) ^ sw) * 8));
  const char* vf0[2][4];                 // V frag, buffer 0
#pragma unroll
  for (int hf = 0; hf < 2; ++hf)
#pragma unroll
    for (int dt = 0; dt < 4; ++dt)
      vf0[hf][dt] = (const char*)(Vs[0] + (dt * 16 + lr) * 64 + (((hf * 4 + lh) ^ sw) * 8));
  uint2* pwp[4];                         // P write slots (not double-buffered)
#pragma unroll
  for (int nt = 0; nt < 4; ++nt)
    pwp[nt] = (uint2*)(Pw + lr * 64 + (((nt * 4 + lh + lr) & 15) * 4));
  const uint2 *prA[2], *prB[2];          // P read slots
#pragma unroll
  for (int hf = 0; hf < 2; ++hf) {
    prA[hf] = (const uint2*)(Pw + lr * 64 + (((hf * 8 + lh * 2 + lr) & 15) * 4));
    prB[hf] = (const uint2*)(Pw + lr * 64 + (((hf * 8 + lh * 2 + 1 + lr) & 15) * 4));
  }

  const unsigned short* Kbase = Kp + (size_t)b * SEQ * DM + h * DH;
  const unsigned short* Vbase = Vt + (size_t)h * DH * (BATCH * SEQ) + (size_t)b * SEQ;

  // per-lane staging pointers (advance by constant strides per tile)
  const int slot0 = w * 64 + lane, slot1 = 256 + w * 64 + lane;
  const int r0 = slot0 >> 3, c0 = (slot0 & 7) ^ (r0 & 7);
  const int r1 = slot1 >> 3, c1 = (slot1 & 7) ^ (r1 & 7);
  const unsigned short* gk0 = Kbase + (size_t)r0 * DM + c0 * 8;
  const unsigned short* gk1 = Kbase + (size_t)r1 * DM + c1 * 8;
  const unsigned short* gv0 = Vbase + (size_t)r0 * (BATCH * SEQ) + c0 * 8;
  const unsigned short* gv1 = Vbase + (size_t)r1 * (BATCH * SEQ) + c1 * 8;
  const int dst0 = (w * 64) * 8, dst1 = (256 + w * 64) * 8;

  auto stage = [&](int buf) {
    __builtin_amdgcn_global_load_lds((gas1)gk0, (las3)(&Ks[buf][dst0]), 16, 0, 0);
    __builtin_amdgcn_global_load_lds((gas1)gk1, (las3)(&Ks[buf][dst1]), 16, 0, 0);
    __builtin_amdgcn_global_load_lds((gas1)gv0, (las3)(&Vs[buf][dst0]), 16, 0, 0);
    __builtin_amdgcn_global_load_lds((gas1)gv1, (las3)(&Vs[buf][dst1]), 16, 0, 0);
    gk0 += 64 * DM; gk1 += 64 * DM; gv0 += 64; gv1 += 64;
  };

  stage(0);
  for (int t = 0; t < 32; ++t) {
    const int cur = t & 1;
    const int curB = cur * (64 * 64 * 2);   // byte offset of active buffer
    if (t < 31) {
      stage(cur ^ 1);                                 // prefetch next tile
      asm volatile("s_waitcnt vmcnt(4)" ::: "memory");// cur's 4 loads done; next 4 in flight
    } else {
      asm volatile("s_waitcnt vmcnt(0)" ::: "memory");
    }
    __builtin_amdgcn_s_barrier();
    __builtin_amdgcn_sched_barrier(0);

    // QK^T (swapped operands): rows = kv, cols = q; output already in exp2 domain
    f32x4 s[2][4] = {};
    __builtin_amdgcn_s_setprio(1);
#pragma unroll
    for (int nt = 0; nt < 4; ++nt) {
#pragma unroll
      for (int kt = 0; kt < 2; ++kt) {
        const s16x8 kf = *(const s16x8*)(kf0[nt][kt] + curB);
        s[0][nt] = __builtin_amdgcn_mfma_f32_16x16x32_bf16(kf, qf[0][kt], s[0][nt], 0, 0, 0);
        s[1][nt] = __builtin_amdgcn_mfma_f32_16x16x32_bf16(kf, qf[1][kt], s[1][nt], 0, 0, 0);
      }
    }
    __builtin_amdgcn_s_setprio(0);

    // online softmax, lane-local (q = lr), defer-max rescale; exp in place,
    // then pack BOTH qb to bf16 regs
    uint2 pk[2][4];
#pragma unroll
    for (int qb = 0; qb < 2; ++qb) {
      const f32x4 m03 = vmax4(vmax4(s[qb][0], s[qb][1]), vmax4(s[qb][2], s[qb][3]));
      float mx = fmaxf(fmaxf(m03[0], m03[1]), fmaxf(m03[2], m03[3]));
      mx = fmaxf(mx, __shfl_xor(mx, 16));
      mx = fmaxf(mx, __shfl_xor(mx, 32));
      if (!__all(mx - m_run[qb] <= 11.5f)) {   // exp2-domain defer threshold
        const float al = __builtin_amdgcn_exp2f(m_run[qb] - mx);
        m_run[qb] = mx;
        l_run[qb] *= al;
#pragma unroll
        for (int dt = 0; dt < 4; ++dt) o[qb][dt] *= al;
      }
      const float base = m_run[qb];
#pragma unroll
      for (int nt = 0; nt < 4; ++nt)
#pragma unroll
        for (int r = 0; r < 4; ++r)
          s[qb][nt][r] = __builtin_amdgcn_exp2f(s[qb][nt][r] - base);
      const f32x4 st = (s[qb][0] + s[qb][1]) + (s[qb][2] + s[qb][3]);
      float rs = (st[0] + st[1]) + (st[2] + st[3]);
      rs += __shfl_xor(rs, 16);
      rs += __shfl_xor(rs, 32);
      l_run[qb] += rs;
#pragma unroll
      for (int nt = 0; nt < 4; ++nt) {
        pk[qb][nt].x = cvt_pk_bf16(s[qb][nt][0], s[qb][nt][1]);
        pk[qb][nt].y = cvt_pk_bf16(s[qb][nt][2], s[qb][nt][3]);
      }
    }

    // V-fragments: each Vs byte read exactly once per wave (8 b128)
    s16x8 vf[8];
#pragma unroll
    for (int hf = 0; hf < 2; ++hf)
#pragma unroll
      for (int dt = 0; dt < 4; ++dt)
        vf[hf * 4 + dt] = *(const s16x8*)(vf0[hf][dt] + curB);

    // PV per qb through the rotated per-wave P buffer; V from registers
#pragma unroll
    for (int qb = 0; qb < 2; ++qb) {
#pragma unroll
      for (int nt = 0; nt < 4; ++nt)
        *pwp[nt] = pk[qb][nt];
#pragma unroll
      for (int hf = 0; hf < 2; ++hf) {
        const uint2 lo = *prA[hf];
        const uint2 hi = *prB[hf];
        u32x4 pu;
        pu[0] = lo.x; pu[1] = lo.y; pu[2] = hi.x; pu[3] = hi.y;
        const s16x8 pf = __builtin_bit_cast(s16x8, pu);
        __builtin_amdgcn_s_setprio(1);
#pragma unroll
        for (int dt = 0; dt < 4; ++dt)
          o[qb][dt] = __builtin_amdgcn_mfma_f32_16x16x32_bf16(vf[hf * 4 + dt], pf, o[qb][dt], 0, 0, 0);
        __builtin_amdgcn_s_setprio(0);
      }
    }
    __builtin_amdgcn_sched_barrier(0);
    __builtin_amdgcn_s_barrier();   // all waves done reading buf[cur] before it's restaged
  }

  // epilogue: normalize, pack pairs, store (O[q=lr][d])
#pragma unroll
  for (int qb = 0; qb < 2; ++qb) {
    const float rl = __builtin_amdgcn_rcpf(l_run[qb]);
    unsigned short* orow = AO + (size_t)(b * SEQ + qt * 128 + w * 32 + qb * 16 + lr) * DM + h * DH;
#pragma unroll
    for (int dt = 0; dt < 4; ++dt) {
      *(unsigned int*)(orow + dt * 16 + lh * 4)     = cvt_pk_bf16(o[qb][dt][0] * rl, o[qb][dt][1] * rl);
      *(unsigned int*)(orow + dt * 16 + lh * 4 + 2) = cvt_pk_bf16(o[qb][dt][2] * rl, o[qb][dt][3] * rl);
    }
  }
}

extern "C" void kernel_launch(void* const* d_in, const int* in_sizes, int n_in,
                              void* d_out, int out_size, void* d_ws, size_t ws_size,
                              hipStream_t stream) {
  const float* q   = (const float*)d_in[0];
  const float* k   = (const float*)d_in[1];
  const float* v   = (const float*)d_in[2];
  const float* W_q = (const float*)d_in[3];
  const float* b_q = (const float*)d_in[4];
  const float* W_k = (const float*)d_in[5];
  const float* b_k = (const float*)d_in[6];
  const float* W_v = (const float*)d_in[7];
  const float* b_v = (const float*)d_in[8];
  const float* W_o = (const float*)d_in[9];
  const float* b_o = (const float*)d_in[10];

  const size_t SD  = (size_t)BATCH * SEQ * DM;          // 8,388,608 elems
  const size_t SDB = SD * 2;                            // bytes per bf16 buffer
  const size_t D2  = (size_t)DM * DM;                   // 1,048,576 elems
  if (ws_size < 5 * SDB + D2 * 2) return;               // ~86 MB

  char* base = (char*)d_ws;
  unsigned short* B0 = (unsigned short*)(base);             // XQ -> AO
  unsigned short* B1 = (unsigned short*)(base + 1 * SDB);   // XK -> Vt
  unsigned short* B2 = (unsigned short*)(base + 2 * SDB);   // XV
  unsigned short* B3 = (unsigned short*)(base + 3 * SDB);   // Qp (pre-scaled)
  unsigned short* B4 = (unsigned short*)(base + 4 * SDB);   // Kp
  unsigned short* Wb = (unsigned short*)(base + 5 * SDB);   // Wo bf16 (2MB)

  // bf16 Wq/Wk/Wv parked in d_out's front 6MB (fully overwritten by O-GEMM later)
  unsigned short* dW0 = (unsigned short*)d_out;             // Wq
  unsigned short* dW1 = dW0 + D2;                           // Wk
  unsigned short* dW2 = dW0 + 2 * D2;                       // Wv

  const int nSD4 = (int)(SD / 4), nD24 = (int)(D2 / 4);
  const dim3 blk(256);

  cvt3_k<<<dim3(nSD4 / 256, 3), blk, 0, stream>>>(q, k, v, B0, B1, B2, nSD4);
  cvt4_k<<<dim3(nD24 / 256, 4), blk, 0, stream>>>(W_q, W_k, W_v, W_o, dW0, dW1, dW2, Wb, nD24);
  // Q and K projections (one dispatch; Q epilogue applies 0.125*log2e)
  gemm_qk<<<dim3(DM / 128, (BATCH * SEQ) / 128, 2), blk, 0, stream>>>(
      B0, B1, dW0, dW1, b_q, b_k, B3, B4, BATCH * SEQ, DM, DM);
  // V projection, transposed output: Vt[d, b*S+s] = (W_v XV^T)[d, i] + b_v[d]
  gemm_bt<true, false><<<dim3((BATCH * SEQ) / 128, DM / 128), blk, 0, stream>>>(
      dW2, B2, b_v, B1, DM, BATCH * SEQ, DM);
  // fused attention
  attn_k<<<dim3(16 * NH * BATCH), blk, 0, stream>>>(B3, B4, B1, B0);
  // output projection -> fp32
  gemm_bt<false, true><<<dim3(DM / 128, (BATCH * SEQ) / 128), blk, 0, stream>>>(
      B0, Wb, b_o, d_out, BATCH * SEQ, DM, DM);
}